// Round 11
// baseline (393.944 us; speedup 1.0000x reference)
//
#include <hip/hip_runtime.h>
#include <hip/hip_bf16.h>

#define DD 128

// ---------------- max depth reduction ----------------
__global__ void k_depthmax(const int* __restrict__ depths, int* __restrict__ maxd, int n){
  int v = 0;
  for (int i = blockIdx.x * blockDim.x + threadIdx.x; i < n; i += gridDim.x * blockDim.x){
    int d = depths[i]; v = d > v ? d : v;
  }
  #pragma unroll
  for (int off = 32; off; off >>= 1){ int o = __shfl_xor(v, off); v = o > v ? o : v; }
  if ((threadIdx.x & 63) == 0) atomicMax(maxd, v);
}

// ---------------- gate MLP: scale_weights (sw[3]), init lc = ba ----------------
__global__ void k_gate(const int* __restrict__ maxd, const float* __restrict__ Wg1,
                       const float* __restrict__ bg1, const float* __restrict__ Wg2,
                       const float* __restrict__ bg2, const float* __restrict__ ba,
                       float* __restrict__ sw, float* __restrict__ lc, float sf0){
  __shared__ float h[32];
  int t = threadIdx.x;
  float sf1 = (float)(*maxd) / 20.0f;
  if (t < 32) h[t] = fmaxf(0.0f, sf0 * Wg1[t] + sf1 * Wg1[32 + t] + bg1[t]);
  __syncthreads();
  if (t < 3){
    float s = bg2[t];
    for (int k = 0; k < 32; ++k) s += h[k] * Wg2[k * 3 + t];
    sw[t] = 1.0f / (1.0f + __expf(-s));
    lc[t] = ba[t];
  }
}

// ---------------- combined matrices V_i = sw_i * Wh_i @ Wf_i,  ob_i = sw_i * bh_i @ Wf_i ----------------
__global__ void k_combine(const float* __restrict__ Wh, const float* __restrict__ bh,
                          const float* __restrict__ Wf, const float* __restrict__ sw,
                          float* __restrict__ V, float* __restrict__ ob){
  int k = blockIdx.x;        // 0..128 (128 == bias row)
  int i = blockIdx.y;        // hop
  int c = threadIdx.x;       // 0..127
  float s = sw[i];
  float acc = 0.0f;
  if (k < DD){
    for (int d = 0; d < DD; ++d)
      acc += Wh[(i * DD + k) * DD + d] * Wf[(i * DD + d) * DD + c];
    V[(i * DD + k) * DD + c] = s * acc;
  } else {
    for (int d = 0; d < DD; ++d)
      acc += bh[i * DD + d] * Wf[(i * DD + d) * DD + c];
    ob[i * DD + c] = s * acc;
  }
}

// ---------------- U_i = sw_i * Wh_i @ Wa_i  and lc += sw_i * bh_i @ Wa_i ----------------
__global__ void k_ua(const float* __restrict__ Wh, const float* __restrict__ bh,
                     const float* __restrict__ Wa, const float* __restrict__ sw,
                     float* __restrict__ U, float* __restrict__ lc){
  int i = blockIdx.x, k = threadIdx.x;
  float s = sw[i];
  float a0 = 0, a1 = 0, a2 = 0;
  for (int d = 0; d < DD; ++d){
    float w = Wh[(i * DD + k) * DD + d];
    a0 += w * Wa[(i * DD + d) * 3 + 0];
    a1 += w * Wa[(i * DD + d) * 3 + 1];
    a2 += w * Wa[(i * DD + d) * 3 + 2];
  }
  U[(i * DD + k) * 3 + 0] = s * a0;
  U[(i * DD + k) * 3 + 1] = s * a1;
  U[(i * DD + k) * 3 + 2] = s * a2;
  if (k < 3){
    float b = 0;
    for (int d = 0; d < DD; ++d) b += bh[i * DD + d] * Wa[(i * DD + d) * 3 + k];
    atomicAdd(&lc[k], s * b);
  }
}

// ---------------- CSR build ----------------
__global__ void k_hist(const int* __restrict__ col, int* __restrict__ cnt, int e){
  for (int i = blockIdx.x * blockDim.x + threadIdx.x; i < e; i += gridDim.x * blockDim.x)
    atomicAdd(&cnt[col[i]], 1);
}

// ---- 3-phase parallel scan: block-local scan -> scan of block totals -> add base ----
__global__ void k_scan1(const int* __restrict__ cnt, int* __restrict__ loc,
                        int* __restrict__ btot, int n){
  __shared__ int sdata[1024];
  int t = threadIdx.x;
  int i = blockIdx.x * 1024 + t;
  int v = (i < n) ? cnt[i] : 0;
  sdata[t] = v;
  __syncthreads();
  for (int d = 1; d < 1024; d <<= 1){
    int a = (t >= d) ? sdata[t - d] : 0;
    __syncthreads();
    sdata[t] += a;
    __syncthreads();
  }
  if (i < n) loc[i] = sdata[t] - v;          // block-local exclusive
  if (t == 1023) btot[blockIdx.x] = sdata[1023];
}

__global__ void k_scan2(const int* __restrict__ btot, int* __restrict__ bbase,
                        int nb, int* __restrict__ offs, int n){
  int lane = threadIdx.x & 63;
  int carry = 0;
  for (int s = 0; s < nb; s += 64){
    int idx = s + lane;
    int v = (idx < nb) ? btot[idx] : 0;
    int incl = v;
    #pragma unroll
    for (int d = 1; d < 64; d <<= 1){
      int o = __shfl_up(incl, d);
      if (lane >= d) incl += o;
    }
    if (idx < nb) bbase[idx] = carry + incl - v;
    carry += __shfl(incl, 63);
  }
  if (lane == 0) offs[n] = carry;
}

__global__ void k_scan3(const int* __restrict__ loc, const int* __restrict__ bbase,
                        int* __restrict__ offs, int* __restrict__ cur, int n){
  int i = blockIdx.x * blockDim.x + threadIdx.x;
  if (i < n){
    int ex = loc[i] + bbase[i >> 10];
    offs[i] = ex;
    cur[i] = ex;
  }
}

__global__ void k_fill(const int* __restrict__ row, const int* __restrict__ col,
                       int* __restrict__ cur, int* __restrict__ srcs, int e){
  for (int i = blockIdx.x * blockDim.x + threadIdx.x; i < e; i += gridDim.x * blockDim.x){
    int c = col[i];
    int p = atomicAdd(&cur[c], 1);
    srcs[p] = row[i];
  }
}

// ---------------- scatter_mean: one node per HALF-WAVE, float4 gathers, unroll-4 ----------------
__global__ void k_agg(const float* __restrict__ src, float* __restrict__ dst,
                      const int* __restrict__ offs, const int* __restrict__ srcs, int n){
  int hw = (blockIdx.x * blockDim.x + threadIdx.x) >> 5;   // half-wave id
  int lane = threadIdx.x & 31;
  int nhw = (gridDim.x * blockDim.x) >> 5;
  const float4* s4 = (const float4*)src;
  for (int node = hw; node < n; node += nhw){
    int o0 = offs[node], o1 = offs[node + 1];
    float ax = 0.0f, ay = 0.0f, az = 0.0f, aw = 0.0f;
    for (int base = o0; base < o1; base += 32){
      int m = o1 - base; if (m > 32) m = 32;
      int myidx = (base + lane < o1) ? srcs[base + lane] : 0;
      int j = 0;
      for (; j + 4 <= m; j += 4){
        int i0 = __shfl(myidx, j, 32);
        int i1 = __shfl(myidx, j + 1, 32);
        int i2 = __shfl(myidx, j + 2, 32);
        int i3 = __shfl(myidx, j + 3, 32);
        float4 v0 = s4[(size_t)i0 * 32 + lane];
        float4 v1 = s4[(size_t)i1 * 32 + lane];
        float4 v2 = s4[(size_t)i2 * 32 + lane];
        float4 v3 = s4[(size_t)i3 * 32 + lane];
        ax += (v0.x + v1.x) + (v2.x + v3.x);
        ay += (v0.y + v1.y) + (v2.y + v3.y);
        az += (v0.z + v1.z) + (v2.z + v3.z);
        aw += (v0.w + v1.w) + (v2.w + v3.w);
      }
      for (; j < m; ++j){
        int s = __shfl(myidx, j, 32);
        float4 v = s4[(size_t)s * 32 + lane];
        ax += v.x; ay += v.y; az += v.z; aw += v.w;
      }
    }
    float inv = 1.0f / fmaxf((float)(o1 - o0), 1.0f);
    ((float4*)dst)[(size_t)node * 32 + lane] = make_float4(ax * inv, ay * inv, az * inv, aw * inv);
  }
}

// ---------------- attention: logits = sum_i c_i @ U_i + lc ; softmax ----------------
__global__ void k_att(const float* __restrict__ c0, const float* __restrict__ c1,
                      const float* __restrict__ c2, const float* __restrict__ U,
                      const float* __restrict__ lc, float* __restrict__ att, int n){
  int wid = (blockIdx.x * blockDim.x + threadIdx.x) >> 6;
  int lane = threadIdx.x & 63;
  int nw = (gridDim.x * blockDim.x) >> 6;
  for (int node = wid; node < n; node += nw){
    float l0 = 0, l1 = 0, l2 = 0;
    {
      float2 v = ((const float2*)c0)[(size_t)node * 64 + lane];
      int k0 = (0 * DD + lane * 2) * 3;
      l0 += v.x * U[k0 + 0] + v.y * U[k0 + 3];
      l1 += v.x * U[k0 + 1] + v.y * U[k0 + 4];
      l2 += v.x * U[k0 + 2] + v.y * U[k0 + 5];
    }
    {
      float2 v = ((const float2*)c1)[(size_t)node * 64 + lane];
      int k0 = (1 * DD + lane * 2) * 3;
      l0 += v.x * U[k0 + 0] + v.y * U[k0 + 3];
      l1 += v.x * U[k0 + 1] + v.y * U[k0 + 4];
      l2 += v.x * U[k0 + 2] + v.y * U[k0 + 5];
    }
    {
      float2 v = ((const float2*)c2)[(size_t)node * 64 + lane];
      int k0 = (2 * DD + lane * 2) * 3;
      l0 += v.x * U[k0 + 0] + v.y * U[k0 + 3];
      l1 += v.x * U[k0 + 1] + v.y * U[k0 + 4];
      l2 += v.x * U[k0 + 2] + v.y * U[k0 + 5];
    }
    #pragma unroll
    for (int off = 32; off; off >>= 1){
      l0 += __shfl_xor(l0, off);
      l1 += __shfl_xor(l1, off);
      l2 += __shfl_xor(l2, off);
    }
    l0 += lc[0]; l1 += lc[1]; l2 += lc[2];
    float m = fmaxf(l0, fmaxf(l1, l2));
    float e0 = __expf(l0 - m), e1 = __expf(l1 - m), e2 = __expf(l2 - m);
    float inv = 1.0f / (e0 + e1 + e2);
    if (lane == 0)
      *(float4*)(att + (size_t)node * 4) = make_float4(e0 * inv, e1 * inv, e2 * inv, 0.0f);
  }
}

// ---------------- fused output GEMM: async global_load_lds double-buffer ----------------
// out = Z @ Vbig + (att·ob + bf); Z[n, i*128+k] = att[n][i] * c_i[n][k].
// Tile 32 nodes x 128 cols, BK=32. LDS = 2*(4KB C + 16KB V) = 40KB -> 4 blocks/CU.
// Staging via __builtin_amdgcn_global_load_lds (16B/lane, fire-and-forget): no VGPRs held
// across compute -> no spill (rounds 9/10: reg-prefetch spilled 170MB/launch to scratch).
// att applied at compute time (Ct holds raw c_i; z *= a per micro-row).
#define BK 32
#define ONT 32

__device__ __forceinline__ void gload16(const void* g, void* l){
  __builtin_amdgcn_global_load_lds((const __attribute__((address_space(1))) void*)g,
                                   (__attribute__((address_space(3))) void*)l, 16, 0, 0);
}

__global__ __launch_bounds__(256, 4) void k_out(
    const float* __restrict__ c0, const float* __restrict__ c1, const float* __restrict__ c2,
    const float* __restrict__ att, const float* __restrict__ V, const float* __restrict__ ob,
    const float* __restrict__ bf, float* __restrict__ out, int n){
  __shared__ float Ct[2][ONT * BK];    // [buf][row*32+k]   4KB each
  __shared__ float Vt[2][BK * DD];     // [buf][krow*128+c] 16KB each
  int nbase = blockIdx.x * ONT;
  int t = threadIdx.x;
  int tIdN = t >> 5;          // 0..7 -> node group of 4
  int tIdC = t & 31;          // col group of 4
  int wv = t >> 6;            // wave 0..3
  int ln = t & 63;            // lane

  // staging geometry (byte offsets; LDS dest = uniform base + lane*16)
  int crow = (wv << 3) + (ln >> 3);          // 0..31: node row this lane fetches
  size_t cgoff = (size_t)(nbase + crow) * (DD * 4) + (size_t)((ln & 7) << 4);
  bool clive = (nbase + crow) < n;

  float acc[4][4];
  #pragma unroll
  for (int a = 0; a < 4; ++a)
    #pragma unroll
    for (int b = 0; b < 4; ++b) acc[a][b] = 0.0f;

  // att rows for this thread's 4 nodes
  float4 an[4];
  #pragma unroll
  for (int nn = 0; nn < 4; ++nn){
    int g2 = nbase + tIdN * 4 + nn;
    an[nn] = (g2 < n) ? *(const float4*)(att + (size_t)g2 * 4) : make_float4(0, 0, 0, 0);
  }

  // stage tile kt into buffer b
  auto stage = [&](int kt, int b){
    int i = kt >> 2;
    int kc0 = (kt & 3) << 5;
    const float* cp = (i == 0) ? c0 : (i == 1) ? c1 : c2;
    if (clive)
      gload16((const char*)cp + cgoff + (size_t)kc0 * 4, (char*)Ct[b] + (wv << 10));
    const char* vg = (const char*)V + (size_t)(i * DD + kc0) * (DD * 4) + (wv << 12);
    char* vl = (char*)Vt[b] + (wv << 12);
    #pragma unroll
    for (int p = 0; p < 4; ++p)
      gload16(vg + (p << 10) + (ln << 4), vl + (p << 10));
  };

  stage(0, 0);   // prologue (async)

  for (int kt = 0; kt < 12; ++kt){
    __syncthreads();                     // drains vmcnt: tile kt resident in buf kt&1
    if (kt < 11) stage(kt + 1, (kt + 1) & 1);   // async into other buffer
    int i = kt >> 2;
    const float* Cb = Ct[kt & 1];
    const float* Vb = Vt[kt & 1];
    float acur[4];
    #pragma unroll
    for (int nn = 0; nn < 4; ++nn)
      acur[nn] = (i == 0) ? an[nn].x : (i == 1) ? an[nn].y : an[nn].z;
    #pragma unroll
    for (int kk = 0; kk < BK; kk += 4){
      float4 z[4];
      #pragma unroll
      for (int nn = 0; nn < 4; ++nn){
        float4 zr = *(const float4*)(&Cb[(tIdN * 4 + nn) * BK + kk]);
        z[nn] = make_float4(zr.x * acur[nn], zr.y * acur[nn], zr.z * acur[nn], zr.w * acur[nn]);
      }
      #pragma unroll
      for (int q = 0; q < 4; ++q){
        float4 v = *(const float4*)(&Vb[(kk + q) * DD + tIdC * 4]);
        #pragma unroll
        for (int nn = 0; nn < 4; ++nn){
          float zz = (q == 0) ? z[nn].x : (q == 1) ? z[nn].y : (q == 2) ? z[nn].z : z[nn].w;
          acc[nn][0] += zz * v.x;
          acc[nn][1] += zz * v.y;
          acc[nn][2] += zz * v.z;
          acc[nn][3] += zz * v.w;
        }
      }
    }
  }
  // epilogue: bias + attention-weighted ob
  int cc = tIdC * 4;
  float4 bb = *(const float4*)(bf + cc);
  float4 o0 = *(const float4*)(ob + 0 * DD + cc);
  float4 o1 = *(const float4*)(ob + 1 * DD + cc);
  float4 o2 = *(const float4*)(ob + 2 * DD + cc);
  #pragma unroll
  for (int nn = 0; nn < 4; ++nn){
    int g2 = nbase + tIdN * 4 + nn;
    if (g2 < n){
      float a0 = an[nn].x, a1 = an[nn].y, a2 = an[nn].z;
      float4 rr;
      rr.x = acc[nn][0] + bb.x + a0 * o0.x + a1 * o1.x + a2 * o2.x;
      rr.y = acc[nn][1] + bb.y + a0 * o0.y + a1 * o1.y + a2 * o2.y;
      rr.z = acc[nn][2] + bb.z + a0 * o0.z + a1 * o1.z + a2 * o2.z;
      rr.w = acc[nn][3] + bb.w + a0 * o0.w + a1 * o1.w + a2 * o2.w;
      *(float4*)(out + (size_t)g2 * DD + cc) = rr;
    }
  }
}

extern "C" void kernel_launch(void* const* d_in, const int* in_sizes, int n_in,
                              void* d_out, int out_size, void* d_ws, size_t ws_size,
                              hipStream_t stream){
  const float* x   = (const float*)d_in[0];
  const int*   ei  = (const int*)d_in[1];
  const int*   dep = (const int*)d_in[2];
  const float* Wh  = (const float*)d_in[3];
  const float* bh  = (const float*)d_in[4];
  const float* Wg1 = (const float*)d_in[5];
  const float* bg1 = (const float*)d_in[6];
  const float* Wg2 = (const float*)d_in[7];
  const float* bg2 = (const float*)d_in[8];
  const float* Wa  = (const float*)d_in[9];
  const float* ba  = (const float*)d_in[10];
  const float* Wf  = (const float*)d_in[11];
  const float* bf  = (const float*)d_in[12];
  float* out = (float*)d_out;

  int N = in_sizes[0] / DD;
  int E = in_sizes[1] / 2;
  if (N <= 0) return;
  const int* row = ei;
  const int* col = ei + E;

  char* w = (char*)d_ws;
  size_t o = 0;
  auto alloc = [&](size_t bytes) -> void* {
    void* p = w + o;
    o += (bytes + 255) & ~(size_t)255;
    return p;
  };
  float* c1   = (float*)alloc((size_t)N * DD * 4);
  float* c2   = (float*)alloc((size_t)N * DD * 4);
  float* att  = (float*)alloc((size_t)N * 4 * 4);
  float* V    = (float*)alloc((size_t)3 * DD * DD * 4);
  float* ob   = (float*)alloc((size_t)3 * DD * 4);
  float* U    = (float*)alloc((size_t)3 * DD * 3 * 4);
  float* lc   = (float*)alloc(16);
  float* sw   = (float*)alloc(16);
  int*   maxd = (int*)alloc(16);
  int*   cnt  = (int*)alloc((size_t)N * 4);
  int*   offs = (int*)alloc((size_t)(N + 1) * 4);
  int*   cur  = (int*)alloc((size_t)N * 4);
  int*   srcs = (int*)alloc((size_t)E * 4);
  int*   loc  = (int*)alloc((size_t)N * 4);
  int    nb   = (N + 1023) / 1024;
  int*   btot = (int*)alloc((size_t)nb * 4);
  int*   bbase= (int*)alloc((size_t)nb * 4);

  hipMemsetAsync(maxd, 0, 4, stream);
  hipMemsetAsync(cnt, 0, (size_t)N * 4, stream);

  k_depthmax<<<128, 256, 0, stream>>>(dep, maxd, N);
  k_gate<<<1, 64, 0, stream>>>(maxd, Wg1, bg1, Wg2, bg2, ba, sw, lc, (float)N / 5000.0f);
  k_combine<<<dim3(129, 3), 128, 0, stream>>>(Wh, bh, Wf, sw, V, ob);
  k_ua<<<3, 128, 0, stream>>>(Wh, bh, Wa, sw, U, lc);
  k_hist<<<(E + 255) / 256, 256, 0, stream>>>(col, cnt, E);
  k_scan1<<<nb, 1024, 0, stream>>>(cnt, loc, btot, N);
  k_scan2<<<1, 64, 0, stream>>>(btot, bbase, nb, offs, N);
  k_scan3<<<(N + 255) / 256, 256, 0, stream>>>(loc, bbase, offs, cur, N);
  k_fill<<<(E + 255) / 256, 256, 0, stream>>>(row, col, cur, srcs, E);
  int aggBlocks = (N + 7) / 8;          // one node per half-wave
  k_agg<<<aggBlocks, 256, 0, stream>>>(x, c1, offs, srcs, N);
  k_agg<<<aggBlocks, 256, 0, stream>>>(c1, c2, offs, srcs, N);
  int attBlocks = (N + 3) / 4;
  k_att<<<attBlocks, 256, 0, stream>>>(x, c1, c2, U, lc, att, N);
  k_out<<<(N + ONT - 1) / ONT, 256, 0, stream>>>(x, c1, c2, att, V, ob, bf, out, N);
}

// Round 12
// 338.216 us; speedup vs baseline: 1.1648x; 1.1648x over previous
//
#include <hip/hip_runtime.h>
#include <hip/hip_bf16.h>

#define DD 128

// ---------------- max depth reduction ----------------
__global__ void k_depthmax(const int* __restrict__ depths, int* __restrict__ maxd, int n){
  int v = 0;
  for (int i = blockIdx.x * blockDim.x + threadIdx.x; i < n; i += gridDim.x * blockDim.x){
    int d = depths[i]; v = d > v ? d : v;
  }
  #pragma unroll
  for (int off = 32; off; off >>= 1){ int o = __shfl_xor(v, off); v = o > v ? o : v; }
  if ((threadIdx.x & 63) == 0) atomicMax(maxd, v);
}

// ---------------- gate MLP: scale_weights (sw[3]), init lc = ba ----------------
__global__ void k_gate(const int* __restrict__ maxd, const float* __restrict__ Wg1,
                       const float* __restrict__ bg1, const float* __restrict__ Wg2,
                       const float* __restrict__ bg2, const float* __restrict__ ba,
                       float* __restrict__ sw, float* __restrict__ lc, float sf0){
  __shared__ float h[32];
  int t = threadIdx.x;
  float sf1 = (float)(*maxd) / 20.0f;
  if (t < 32) h[t] = fmaxf(0.0f, sf0 * Wg1[t] + sf1 * Wg1[32 + t] + bg1[t]);
  __syncthreads();
  if (t < 3){
    float s = bg2[t];
    for (int k = 0; k < 32; ++k) s += h[k] * Wg2[k * 3 + t];
    sw[t] = 1.0f / (1.0f + __expf(-s));
    lc[t] = ba[t];
  }
}

// ---------------- combined matrices V_i = sw_i * Wh_i @ Wf_i,  ob_i = sw_i * bh_i @ Wf_i ----------------
__global__ void k_combine(const float* __restrict__ Wh, const float* __restrict__ bh,
                          const float* __restrict__ Wf, const float* __restrict__ sw,
                          float* __restrict__ V, float* __restrict__ ob){
  int k = blockIdx.x;        // 0..128 (128 == bias row)
  int i = blockIdx.y;        // hop
  int c = threadIdx.x;       // 0..127
  float s = sw[i];
  float acc = 0.0f;
  if (k < DD){
    for (int d = 0; d < DD; ++d)
      acc += Wh[(i * DD + k) * DD + d] * Wf[(i * DD + d) * DD + c];
    V[(i * DD + k) * DD + c] = s * acc;
  } else {
    for (int d = 0; d < DD; ++d)
      acc += bh[i * DD + d] * Wf[(i * DD + d) * DD + c];
    ob[i * DD + c] = s * acc;
  }
}

// ---------------- U_i = sw_i * Wh_i @ Wa_i  and lc += sw_i * bh_i @ Wa_i ----------------
__global__ void k_ua(const float* __restrict__ Wh, const float* __restrict__ bh,
                     const float* __restrict__ Wa, const float* __restrict__ sw,
                     float* __restrict__ U, float* __restrict__ lc){
  int i = blockIdx.x, k = threadIdx.x;
  float s = sw[i];
  float a0 = 0, a1 = 0, a2 = 0;
  for (int d = 0; d < DD; ++d){
    float w = Wh[(i * DD + k) * DD + d];
    a0 += w * Wa[(i * DD + d) * 3 + 0];
    a1 += w * Wa[(i * DD + d) * 3 + 1];
    a2 += w * Wa[(i * DD + d) * 3 + 2];
  }
  U[(i * DD + k) * 3 + 0] = s * a0;
  U[(i * DD + k) * 3 + 1] = s * a1;
  U[(i * DD + k) * 3 + 2] = s * a2;
  if (k < 3){
    float b = 0;
    for (int d = 0; d < DD; ++d) b += bh[i * DD + d] * Wa[(i * DD + d) * 3 + k];
    atomicAdd(&lc[k], s * b);
  }
}

// ---------------- CSR build ----------------
__global__ void k_hist(const int* __restrict__ col, int* __restrict__ cnt, int e){
  for (int i = blockIdx.x * blockDim.x + threadIdx.x; i < e; i += gridDim.x * blockDim.x)
    atomicAdd(&cnt[col[i]], 1);
}

// ---- 3-phase parallel scan: block-local scan -> scan of block totals -> add base ----
__global__ void k_scan1(const int* __restrict__ cnt, int* __restrict__ loc,
                        int* __restrict__ btot, int n){
  __shared__ int sdata[1024];
  int t = threadIdx.x;
  int i = blockIdx.x * 1024 + t;
  int v = (i < n) ? cnt[i] : 0;
  sdata[t] = v;
  __syncthreads();
  for (int d = 1; d < 1024; d <<= 1){
    int a = (t >= d) ? sdata[t - d] : 0;
    __syncthreads();
    sdata[t] += a;
    __syncthreads();
  }
  if (i < n) loc[i] = sdata[t] - v;          // block-local exclusive
  if (t == 1023) btot[blockIdx.x] = sdata[1023];
}

__global__ void k_scan2(const int* __restrict__ btot, int* __restrict__ bbase,
                        int nb, int* __restrict__ offs, int n){
  int lane = threadIdx.x & 63;
  int carry = 0;
  for (int s = 0; s < nb; s += 64){
    int idx = s + lane;
    int v = (idx < nb) ? btot[idx] : 0;
    int incl = v;
    #pragma unroll
    for (int d = 1; d < 64; d <<= 1){
      int o = __shfl_up(incl, d);
      if (lane >= d) incl += o;
    }
    if (idx < nb) bbase[idx] = carry + incl - v;
    carry += __shfl(incl, 63);
  }
  if (lane == 0) offs[n] = carry;
}

__global__ void k_scan3(const int* __restrict__ loc, const int* __restrict__ bbase,
                        int* __restrict__ offs, int* __restrict__ cur, int n){
  int i = blockIdx.x * blockDim.x + threadIdx.x;
  if (i < n){
    int ex = loc[i] + bbase[i >> 10];
    offs[i] = ex;
    cur[i] = ex;
  }
}

__global__ void k_fill(const int* __restrict__ row, const int* __restrict__ col,
                       int* __restrict__ cur, int* __restrict__ srcs, int e){
  for (int i = blockIdx.x * blockDim.x + threadIdx.x; i < e; i += gridDim.x * blockDim.x){
    int c = col[i];
    int p = atomicAdd(&cur[c], 1);
    srcs[p] = row[i];
  }
}

// ---------------- scatter_mean: one node per HALF-WAVE, float4 gathers, unroll-4 ----------------
__global__ void k_agg(const float* __restrict__ src, float* __restrict__ dst,
                      const int* __restrict__ offs, const int* __restrict__ srcs, int n){
  int hw = (blockIdx.x * blockDim.x + threadIdx.x) >> 5;   // half-wave id
  int lane = threadIdx.x & 31;
  int nhw = (gridDim.x * blockDim.x) >> 5;
  const float4* s4 = (const float4*)src;
  for (int node = hw; node < n; node += nhw){
    int o0 = offs[node], o1 = offs[node + 1];
    float ax = 0.0f, ay = 0.0f, az = 0.0f, aw = 0.0f;
    for (int base = o0; base < o1; base += 32){
      int m = o1 - base; if (m > 32) m = 32;
      int myidx = (base + lane < o1) ? srcs[base + lane] : 0;
      int j = 0;
      for (; j + 4 <= m; j += 4){
        int i0 = __shfl(myidx, j, 32);
        int i1 = __shfl(myidx, j + 1, 32);
        int i2 = __shfl(myidx, j + 2, 32);
        int i3 = __shfl(myidx, j + 3, 32);
        float4 v0 = s4[(size_t)i0 * 32 + lane];
        float4 v1 = s4[(size_t)i1 * 32 + lane];
        float4 v2 = s4[(size_t)i2 * 32 + lane];
        float4 v3 = s4[(size_t)i3 * 32 + lane];
        ax += (v0.x + v1.x) + (v2.x + v3.x);
        ay += (v0.y + v1.y) + (v2.y + v3.y);
        az += (v0.z + v1.z) + (v2.z + v3.z);
        aw += (v0.w + v1.w) + (v2.w + v3.w);
      }
      for (; j < m; ++j){
        int s = __shfl(myidx, j, 32);
        float4 v = s4[(size_t)s * 32 + lane];
        ax += v.x; ay += v.y; az += v.z; aw += v.w;
      }
    }
    float inv = 1.0f / fmaxf((float)(o1 - o0), 1.0f);
    ((float4*)dst)[(size_t)node * 32 + lane] = make_float4(ax * inv, ay * inv, az * inv, aw * inv);
  }
}

// ---------------- attention: logits = sum_i c_i @ U_i + lc ; softmax ----------------
__global__ void k_att(const float* __restrict__ c0, const float* __restrict__ c1,
                      const float* __restrict__ c2, const float* __restrict__ U,
                      const float* __restrict__ lc, float* __restrict__ att, int n){
  int wid = (blockIdx.x * blockDim.x + threadIdx.x) >> 6;
  int lane = threadIdx.x & 63;
  int nw = (gridDim.x * blockDim.x) >> 6;
  for (int node = wid; node < n; node += nw){
    float l0 = 0, l1 = 0, l2 = 0;
    {
      float2 v = ((const float2*)c0)[(size_t)node * 64 + lane];
      int k0 = (0 * DD + lane * 2) * 3;
      l0 += v.x * U[k0 + 0] + v.y * U[k0 + 3];
      l1 += v.x * U[k0 + 1] + v.y * U[k0 + 4];
      l2 += v.x * U[k0 + 2] + v.y * U[k0 + 5];
    }
    {
      float2 v = ((const float2*)c1)[(size_t)node * 64 + lane];
      int k0 = (1 * DD + lane * 2) * 3;
      l0 += v.x * U[k0 + 0] + v.y * U[k0 + 3];
      l1 += v.x * U[k0 + 1] + v.y * U[k0 + 4];
      l2 += v.x * U[k0 + 2] + v.y * U[k0 + 5];
    }
    {
      float2 v = ((const float2*)c2)[(size_t)node * 64 + lane];
      int k0 = (2 * DD + lane * 2) * 3;
      l0 += v.x * U[k0 + 0] + v.y * U[k0 + 3];
      l1 += v.x * U[k0 + 1] + v.y * U[k0 + 4];
      l2 += v.x * U[k0 + 2] + v.y * U[k0 + 5];
    }
    #pragma unroll
    for (int off = 32; off; off >>= 1){
      l0 += __shfl_xor(l0, off);
      l1 += __shfl_xor(l1, off);
      l2 += __shfl_xor(l2, off);
    }
    l0 += lc[0]; l1 += lc[1]; l2 += lc[2];
    float m = fmaxf(l0, fmaxf(l1, l2));
    float e0 = __expf(l0 - m), e1 = __expf(l1 - m), e2 = __expf(l2 - m);
    float inv = 1.0f / (e0 + e1 + e2);
    if (lane == 0)
      *(float4*)(att + (size_t)node * 4) = make_float4(e0 * inv, e1 * inv, e2 * inv, 0.0f);
  }
}

// ---------------- fused output GEMM: out = Z @ Vbig + (att·ob + bf) ----------------
// Z[n, i*128+k] = att[n][i] * c_i[n][k], formed at staging time.
// Round-6 proven SYNC structure (no reg prefetch, no async -> no scratch spill;
// rounds 9-11: every pipelined variant spilled ~190MB/launch to scratch and was slower).
// ONT=32 -> grid 1563 (~6 blocks/CU): cross-block overlap hides staging latency
// (round-11 counter evidence: ONT 64->32 raised occupancy 20%->34%).
#define BK 32
#define ONT 32
__global__ __launch_bounds__(256) void k_out(
    const float* __restrict__ c0, const float* __restrict__ c1, const float* __restrict__ c2,
    const float* __restrict__ att, const float* __restrict__ V, const float* __restrict__ ob,
    const float* __restrict__ bf, float* __restrict__ out, int n){
  __shared__ float Ct[ONT][BK + 4];   // 32 nodes x 32 k (padded)  4.6KB
  __shared__ float Vt[BK][DD];        // 32 k x 128 cols          16.4KB
  int nbase = blockIdx.x * ONT;
  int t = threadIdx.x;
  int tIdN = t >> 5;      // 0..7 -> node group of 4
  int tIdC = t & 31;      // col group of 4
  float acc[4][4];
  #pragma unroll
  for (int a = 0; a < 4; ++a)
    #pragma unroll
    for (int b = 0; b < 4; ++b) acc[a][b] = 0.0f;

  for (int kt = 0; kt < 12; ++kt){
    int i = kt >> 2;              // hop
    int kc0 = (kt & 3) << 5;      // 0,32,64,96 within the hop's 128 k
    const float* cp = (i == 0) ? c0 : (i == 1) ? c1 : c2;
    __syncthreads();
    // stage Z tile (att folded in): 32 rows x 32 cols, 1 float4/thread
    {
      int r = t >> 3;              // 0..31
      int cq = (t & 7) << 2;       // 0,4,..,28
      int gn = nbase + r;
      float4 v = make_float4(0, 0, 0, 0);
      float a = 0.0f;
      if (gn < n){
        v = *(const float4*)(cp + (size_t)gn * DD + kc0 + cq);
        a = att[gn * 4 + i];
      }
      *(float4*)(&Ct[r][cq]) = make_float4(v.x * a, v.y * a, v.z * a, v.w * a);
    }
    // stage V tile: 32 rows x 128 cols, 4 float4/thread
    {
      int vr = t >> 5;             // 0..7
      int vc = (t & 31) << 2;      // 0..124
      #pragma unroll
      for (int p = 0; p < 4; ++p){
        int rr = vr + p * 8;
        *(float4*)(&Vt[rr][vc]) = *(const float4*)(V + (size_t)(i * DD + kc0 + rr) * DD + vc);
      }
    }
    __syncthreads();
    // GEMM on the tile
    #pragma unroll
    for (int kk = 0; kk < BK; kk += 4){
      float4 z[4];
      #pragma unroll
      for (int nn = 0; nn < 4; ++nn) z[nn] = *(const float4*)(&Ct[tIdN * 4 + nn][kk]);
      #pragma unroll
      for (int q = 0; q < 4; ++q){
        float4 v = *(const float4*)(&Vt[kk + q][tIdC * 4]);
        #pragma unroll
        for (int nn = 0; nn < 4; ++nn){
          float zz = (q == 0) ? z[nn].x : (q == 1) ? z[nn].y : (q == 2) ? z[nn].z : z[nn].w;
          acc[nn][0] += zz * v.x;
          acc[nn][1] += zz * v.y;
          acc[nn][2] += zz * v.z;
          acc[nn][3] += zz * v.w;
        }
      }
    }
  }
  // epilogue: bias + attention-weighted ob
  int cc = tIdC * 4;
  float4 bb = *(const float4*)(bf + cc);
  float4 o0 = *(const float4*)(ob + 0 * DD + cc);
  float4 o1 = *(const float4*)(ob + 1 * DD + cc);
  float4 o2 = *(const float4*)(ob + 2 * DD + cc);
  #pragma unroll
  for (int nn = 0; nn < 4; ++nn){
    int g2 = nbase + tIdN * 4 + nn;
    if (g2 < n){
      float a0 = att[g2 * 4 + 0], a1 = att[g2 * 4 + 1], a2 = att[g2 * 4 + 2];
      float4 rr;
      rr.x = acc[nn][0] + bb.x + a0 * o0.x + a1 * o1.x + a2 * o2.x;
      rr.y = acc[nn][1] + bb.y + a0 * o0.y + a1 * o1.y + a2 * o2.y;
      rr.z = acc[nn][2] + bb.z + a0 * o0.z + a1 * o1.z + a2 * o2.z;
      rr.w = acc[nn][3] + bb.w + a0 * o0.w + a1 * o1.w + a2 * o2.w;
      *(float4*)(out + (size_t)g2 * DD + cc) = rr;
    }
  }
}

extern "C" void kernel_launch(void* const* d_in, const int* in_sizes, int n_in,
                              void* d_out, int out_size, void* d_ws, size_t ws_size,
                              hipStream_t stream){
  const float* x   = (const float*)d_in[0];
  const int*   ei  = (const int*)d_in[1];
  const int*   dep = (const int*)d_in[2];
  const float* Wh  = (const float*)d_in[3];
  const float* bh  = (const float*)d_in[4];
  const float* Wg1 = (const float*)d_in[5];
  const float* bg1 = (const float*)d_in[6];
  const float* Wg2 = (const float*)d_in[7];
  const float* bg2 = (const float*)d_in[8];
  const float* Wa  = (const float*)d_in[9];
  const float* ba  = (const float*)d_in[10];
  const float* Wf  = (const float*)d_in[11];
  const float* bf  = (const float*)d_in[12];
  float* out = (float*)d_out;

  int N = in_sizes[0] / DD;
  int E = in_sizes[1] / 2;
  if (N <= 0) return;
  const int* row = ei;
  const int* col = ei + E;

  char* w = (char*)d_ws;
  size_t o = 0;
  auto alloc = [&](size_t bytes) -> void* {
    void* p = w + o;
    o += (bytes + 255) & ~(size_t)255;
    return p;
  };
  float* c1   = (float*)alloc((size_t)N * DD * 4);
  float* c2   = (float*)alloc((size_t)N * DD * 4);
  float* att  = (float*)alloc((size_t)N * 4 * 4);
  float* V    = (float*)alloc((size_t)3 * DD * DD * 4);
  float* ob   = (float*)alloc((size_t)3 * DD * 4);
  float* U    = (float*)alloc((size_t)3 * DD * 3 * 4);
  float* lc   = (float*)alloc(16);
  float* sw   = (float*)alloc(16);
  int*   maxd = (int*)alloc(16);
  int*   cnt  = (int*)alloc((size_t)N * 4);
  int*   offs = (int*)alloc((size_t)(N + 1) * 4);
  int*   cur  = (int*)alloc((size_t)N * 4);
  int*   srcs = (int*)alloc((size_t)E * 4);
  int*   loc  = (int*)alloc((size_t)N * 4);
  int    nb   = (N + 1023) / 1024;
  int*   btot = (int*)alloc((size_t)nb * 4);
  int*   bbase= (int*)alloc((size_t)nb * 4);

  hipMemsetAsync(maxd, 0, 4, stream);
  hipMemsetAsync(cnt, 0, (size_t)N * 4, stream);

  k_depthmax<<<128, 256, 0, stream>>>(dep, maxd, N);
  k_gate<<<1, 64, 0, stream>>>(maxd, Wg1, bg1, Wg2, bg2, ba, sw, lc, (float)N / 5000.0f);
  k_combine<<<dim3(129, 3), 128, 0, stream>>>(Wh, bh, Wf, sw, V, ob);
  k_ua<<<3, 128, 0, stream>>>(Wh, bh, Wa, sw, U, lc);
  k_hist<<<(E + 255) / 256, 256, 0, stream>>>(col, cnt, E);
  k_scan1<<<nb, 1024, 0, stream>>>(cnt, loc, btot, N);
  k_scan2<<<1, 64, 0, stream>>>(btot, bbase, nb, offs, N);
  k_scan3<<<(N + 255) / 256, 256, 0, stream>>>(loc, bbase, offs, cur, N);
  k_fill<<<(E + 255) / 256, 256, 0, stream>>>(row, col, cur, srcs, E);
  int aggBlocks = (N + 7) / 8;          // one node per half-wave
  k_agg<<<aggBlocks, 256, 0, stream>>>(x, c1, offs, srcs, N);
  k_agg<<<aggBlocks, 256, 0, stream>>>(c1, c2, offs, srcs, N);
  int attBlocks = (N + 3) / 4;
  k_att<<<attBlocks, 256, 0, stream>>>(x, c1, c2, U, lc, att, N);
  k_out<<<(N + ONT - 1) / ONT, 256, 0, stream>>>(x, c1, c2, att, V, ob, bf, out, N);
}

// Round 13
// 280.356 us; speedup vs baseline: 1.4052x; 1.2064x over previous
//
#include <hip/hip_runtime.h>
#include <hip/hip_bf16.h>

#define DD 128

__device__ __forceinline__ float b2f(unsigned short u){
  return __uint_as_float((unsigned int)u << 16);
}
__device__ __forceinline__ unsigned short f2b(float f){
  unsigned int u = __float_as_uint(f);
  unsigned int r = (u + 0x7FFFu + ((u >> 16) & 1u)) >> 16;   // RNE
  return (unsigned short)r;
}

// ---------------- max depth reduction ----------------
__global__ void k_depthmax(const int* __restrict__ depths, int* __restrict__ maxd, int n){
  int v = 0;
  for (int i = blockIdx.x * blockDim.x + threadIdx.x; i < n; i += gridDim.x * blockDim.x){
    int d = depths[i]; v = d > v ? d : v;
  }
  #pragma unroll
  for (int off = 32; off; off >>= 1){ int o = __shfl_xor(v, off); v = o > v ? o : v; }
  if ((threadIdx.x & 63) == 0) atomicMax(maxd, v);
}

// ---------------- cast x -> bf16 shadow ----------------
__global__ void k_cast(const float* __restrict__ x, unsigned short* __restrict__ xb, int total4){
  int i = blockIdx.x * blockDim.x + threadIdx.x;
  if (i < total4){
    float4 v = ((const float4*)x)[i];
    ushort4 w;
    w.x = f2b(v.x); w.y = f2b(v.y); w.z = f2b(v.z); w.w = f2b(v.w);
    ((ushort4*)xb)[i] = w;
  }
}

// ---------------- gate MLP: scale_weights (sw[3]), init lc = ba ----------------
__global__ void k_gate(const int* __restrict__ maxd, const float* __restrict__ Wg1,
                       const float* __restrict__ bg1, const float* __restrict__ Wg2,
                       const float* __restrict__ bg2, const float* __restrict__ ba,
                       float* __restrict__ sw, float* __restrict__ lc, float sf0){
  __shared__ float h[32];
  int t = threadIdx.x;
  float sf1 = (float)(*maxd) / 20.0f;
  if (t < 32) h[t] = fmaxf(0.0f, sf0 * Wg1[t] + sf1 * Wg1[32 + t] + bg1[t]);
  __syncthreads();
  if (t < 3){
    float s = bg2[t];
    for (int k = 0; k < 32; ++k) s += h[k] * Wg2[k * 3 + t];
    sw[t] = 1.0f / (1.0f + __expf(-s));
    lc[t] = ba[t];
  }
}

// ---------------- combined matrices V_i = sw_i * Wh_i @ Wf_i,  ob_i = sw_i * bh_i @ Wf_i ----------------
__global__ void k_combine(const float* __restrict__ Wh, const float* __restrict__ bh,
                          const float* __restrict__ Wf, const float* __restrict__ sw,
                          float* __restrict__ V, float* __restrict__ ob){
  int k = blockIdx.x;
  int i = blockIdx.y;
  int c = threadIdx.x;
  float s = sw[i];
  float acc = 0.0f;
  if (k < DD){
    for (int d = 0; d < DD; ++d)
      acc += Wh[(i * DD + k) * DD + d] * Wf[(i * DD + d) * DD + c];
    V[(i * DD + k) * DD + c] = s * acc;
  } else {
    for (int d = 0; d < DD; ++d)
      acc += bh[i * DD + d] * Wf[(i * DD + d) * DD + c];
    ob[i * DD + c] = s * acc;
  }
}

// ---------------- U_i = sw_i * Wh_i @ Wa_i  and lc += sw_i * bh_i @ Wa_i ----------------
__global__ void k_ua(const float* __restrict__ Wh, const float* __restrict__ bh,
                     const float* __restrict__ Wa, const float* __restrict__ sw,
                     float* __restrict__ U, float* __restrict__ lc){
  int i = blockIdx.x, k = threadIdx.x;
  float s = sw[i];
  float a0 = 0, a1 = 0, a2 = 0;
  for (int d = 0; d < DD; ++d){
    float w = Wh[(i * DD + k) * DD + d];
    a0 += w * Wa[(i * DD + d) * 3 + 0];
    a1 += w * Wa[(i * DD + d) * 3 + 1];
    a2 += w * Wa[(i * DD + d) * 3 + 2];
  }
  U[(i * DD + k) * 3 + 0] = s * a0;
  U[(i * DD + k) * 3 + 1] = s * a1;
  U[(i * DD + k) * 3 + 2] = s * a2;
  if (k < 3){
    float b = 0;
    for (int d = 0; d < DD; ++d) b += bh[i * DD + d] * Wa[(i * DD + d) * 3 + k];
    atomicAdd(&lc[k], s * b);
  }
}

// ---------------- CSR build ----------------
__global__ void k_hist(const int* __restrict__ col, int* __restrict__ cnt, int e){
  for (int i = blockIdx.x * blockDim.x + threadIdx.x; i < e; i += gridDim.x * blockDim.x)
    atomicAdd(&cnt[col[i]], 1);
}

__global__ void k_scan1(const int* __restrict__ cnt, int* __restrict__ loc,
                        int* __restrict__ btot, int n){
  __shared__ int sdata[1024];
  int t = threadIdx.x;
  int i = blockIdx.x * 1024 + t;
  int v = (i < n) ? cnt[i] : 0;
  sdata[t] = v;
  __syncthreads();
  for (int d = 1; d < 1024; d <<= 1){
    int a = (t >= d) ? sdata[t - d] : 0;
    __syncthreads();
    sdata[t] += a;
    __syncthreads();
  }
  if (i < n) loc[i] = sdata[t] - v;
  if (t == 1023) btot[blockIdx.x] = sdata[1023];
}

__global__ void k_scan2(const int* __restrict__ btot, int* __restrict__ bbase,
                        int nb, int* __restrict__ offs, int n){
  int lane = threadIdx.x & 63;
  int carry = 0;
  for (int s = 0; s < nb; s += 64){
    int idx = s + lane;
    int v = (idx < nb) ? btot[idx] : 0;
    int incl = v;
    #pragma unroll
    for (int d = 1; d < 64; d <<= 1){
      int o = __shfl_up(incl, d);
      if (lane >= d) incl += o;
    }
    if (idx < nb) bbase[idx] = carry + incl - v;
    carry += __shfl(incl, 63);
  }
  if (lane == 0) offs[n] = carry;
}

__global__ void k_scan3(const int* __restrict__ loc, const int* __restrict__ bbase,
                        int* __restrict__ offs, int* __restrict__ cur, int n){
  int i = blockIdx.x * blockDim.x + threadIdx.x;
  if (i < n){
    int ex = loc[i] + bbase[i >> 10];
    offs[i] = ex;
    cur[i] = ex;
  }
}

__global__ void k_fill(const int* __restrict__ row, const int* __restrict__ col,
                       int* __restrict__ cur, int* __restrict__ srcs, int e){
  for (int i = blockIdx.x * blockDim.x + threadIdx.x; i < e; i += gridDim.x * blockDim.x){
    int c = col[i];
    int p = atomicAdd(&cur[c], 1);
    srcs[p] = row[i];
  }
}

// ---------------- scatter_mean over bf16 rows: one node per HALF-WAVE ----------------
// src/dst are bf16 [n][128] (256B rows). fp32 accumulate, RNE bf16 store.
__global__ void k_agg(const unsigned short* __restrict__ src, unsigned short* __restrict__ dst,
                      const int* __restrict__ offs, const int* __restrict__ srcs, int n){
  int hw = (blockIdx.x * blockDim.x + threadIdx.x) >> 5;
  int lane = threadIdx.x & 31;
  int nhw = (gridDim.x * blockDim.x) >> 5;
  const ushort4* s4 = (const ushort4*)src;     // 32 × ushort4 per row
  for (int node = hw; node < n; node += nhw){
    int o0 = offs[node], o1 = offs[node + 1];
    float ax = 0.0f, ay = 0.0f, az = 0.0f, aw = 0.0f;
    for (int base = o0; base < o1; base += 32){
      int m = o1 - base; if (m > 32) m = 32;
      int myidx = (base + lane < o1) ? srcs[base + lane] : 0;
      int j = 0;
      for (; j + 4 <= m; j += 4){
        int i0 = __shfl(myidx, j, 32);
        int i1 = __shfl(myidx, j + 1, 32);
        int i2 = __shfl(myidx, j + 2, 32);
        int i3 = __shfl(myidx, j + 3, 32);
        ushort4 v0 = s4[(size_t)i0 * 32 + lane];
        ushort4 v1 = s4[(size_t)i1 * 32 + lane];
        ushort4 v2 = s4[(size_t)i2 * 32 + lane];
        ushort4 v3 = s4[(size_t)i3 * 32 + lane];
        ax += (b2f(v0.x) + b2f(v1.x)) + (b2f(v2.x) + b2f(v3.x));
        ay += (b2f(v0.y) + b2f(v1.y)) + (b2f(v2.y) + b2f(v3.y));
        az += (b2f(v0.z) + b2f(v1.z)) + (b2f(v2.z) + b2f(v3.z));
        aw += (b2f(v0.w) + b2f(v1.w)) + (b2f(v2.w) + b2f(v3.w));
      }
      for (; j < m; ++j){
        int s = __shfl(myidx, j, 32);
        ushort4 v = s4[(size_t)s * 32 + lane];
        ax += b2f(v.x); ay += b2f(v.y); az += b2f(v.z); aw += b2f(v.w);
      }
    }
    float inv = 1.0f / fmaxf((float)(o1 - o0), 1.0f);
    ushort4 r;
    r.x = f2b(ax * inv); r.y = f2b(ay * inv); r.z = f2b(az * inv); r.w = f2b(aw * inv);
    ((ushort4*)dst)[(size_t)node * 32 + lane] = r;
  }
}

// ---------------- attention: logits = x@U_0 + c1@U_1 + c2@U_2 + lc ; softmax ----------------
__global__ void k_att(const float* __restrict__ c0, const unsigned short* __restrict__ c1b,
                      const unsigned short* __restrict__ c2b, const float* __restrict__ U,
                      const float* __restrict__ lc, float* __restrict__ att, int n){
  int wid = (blockIdx.x * blockDim.x + threadIdx.x) >> 6;
  int lane = threadIdx.x & 63;
  int nw = (gridDim.x * blockDim.x) >> 6;
  for (int node = wid; node < n; node += nw){
    float l0 = 0, l1 = 0, l2 = 0;
    {
      float2 v = ((const float2*)c0)[(size_t)node * 64 + lane];
      int k0 = (0 * DD + lane * 2) * 3;
      l0 += v.x * U[k0 + 0] + v.y * U[k0 + 3];
      l1 += v.x * U[k0 + 1] + v.y * U[k0 + 4];
      l2 += v.x * U[k0 + 2] + v.y * U[k0 + 5];
    }
    {
      ushort2 w = ((const ushort2*)c1b)[(size_t)node * 64 + lane];
      float vx = b2f(w.x), vy = b2f(w.y);
      int k0 = (1 * DD + lane * 2) * 3;
      l0 += vx * U[k0 + 0] + vy * U[k0 + 3];
      l1 += vx * U[k0 + 1] + vy * U[k0 + 4];
      l2 += vx * U[k0 + 2] + vy * U[k0 + 5];
    }
    {
      ushort2 w = ((const ushort2*)c2b)[(size_t)node * 64 + lane];
      float vx = b2f(w.x), vy = b2f(w.y);
      int k0 = (2 * DD + lane * 2) * 3;
      l0 += vx * U[k0 + 0] + vy * U[k0 + 3];
      l1 += vx * U[k0 + 1] + vy * U[k0 + 4];
      l2 += vx * U[k0 + 2] + vy * U[k0 + 5];
    }
    #pragma unroll
    for (int off = 32; off; off >>= 1){
      l0 += __shfl_xor(l0, off);
      l1 += __shfl_xor(l1, off);
      l2 += __shfl_xor(l2, off);
    }
    l0 += lc[0]; l1 += lc[1]; l2 += lc[2];
    float m = fmaxf(l0, fmaxf(l1, l2));
    float e0 = __expf(l0 - m), e1 = __expf(l1 - m), e2 = __expf(l2 - m);
    float inv = 1.0f / (e0 + e1 + e2);
    if (lane == 0)
      *(float4*)(att + (size_t)node * 4) = make_float4(e0 * inv, e1 * inv, e2 * inv, 0.0f);
  }
}

// ---------------- fused output GEMM: out = Z @ Vbig + (att·ob + bf) ----------------
// Round-12 proven SYNC structure (no pipelining -> no spill). Hop 0 from fp32 x;
// hops 1,2 from bf16 c1/c2 (halves their fetch).
#define BK 32
#define ONT 32
__global__ __launch_bounds__(256) void k_out(
    const float* __restrict__ c0, const unsigned short* __restrict__ c1b,
    const unsigned short* __restrict__ c2b,
    const float* __restrict__ att, const float* __restrict__ V, const float* __restrict__ ob,
    const float* __restrict__ bf, float* __restrict__ out, int n){
  __shared__ float Ct[ONT][BK + 4];
  __shared__ float Vt[BK][DD];
  int nbase = blockIdx.x * ONT;
  int t = threadIdx.x;
  int tIdN = t >> 5;
  int tIdC = t & 31;
  float acc[4][4];
  #pragma unroll
  for (int a = 0; a < 4; ++a)
    #pragma unroll
    for (int b = 0; b < 4; ++b) acc[a][b] = 0.0f;

  for (int kt = 0; kt < 12; ++kt){
    int i = kt >> 2;
    int kc0 = (kt & 3) << 5;
    __syncthreads();
    // stage Z tile (att folded in): 32 rows x 32 cols, 4 floats/thread
    {
      int r = t >> 3;
      int cq = (t & 7) << 2;
      int gn = nbase + r;
      float4 v = make_float4(0, 0, 0, 0);
      float a = 0.0f;
      if (gn < n){
        a = att[gn * 4 + i];
        if (i == 0){
          v = *(const float4*)(c0 + (size_t)gn * DD + kc0 + cq);
        } else {
          const unsigned short* cb = (i == 1) ? c1b : c2b;
          ushort4 w = *(const ushort4*)(cb + (size_t)gn * DD + kc0 + cq);
          v = make_float4(b2f(w.x), b2f(w.y), b2f(w.z), b2f(w.w));
        }
      }
      *(float4*)(&Ct[r][cq]) = make_float4(v.x * a, v.y * a, v.z * a, v.w * a);
    }
    // stage V tile: 32 rows x 128 cols, 4 float4/thread
    {
      int vr = t >> 5;
      int vc = (t & 31) << 2;
      #pragma unroll
      for (int p = 0; p < 4; ++p){
        int rr = vr + p * 8;
        *(float4*)(&Vt[rr][vc]) = *(const float4*)(V + (size_t)(i * DD + kc0 + rr) * DD + vc);
      }
    }
    __syncthreads();
    #pragma unroll
    for (int kk = 0; kk < BK; kk += 4){
      float4 z[4];
      #pragma unroll
      for (int nn = 0; nn < 4; ++nn) z[nn] = *(const float4*)(&Ct[tIdN * 4 + nn][kk]);
      #pragma unroll
      for (int q = 0; q < 4; ++q){
        float4 v = *(const float4*)(&Vt[kk + q][tIdC * 4]);
        #pragma unroll
        for (int nn = 0; nn < 4; ++nn){
          float zz = (q == 0) ? z[nn].x : (q == 1) ? z[nn].y : (q == 2) ? z[nn].z : z[nn].w;
          acc[nn][0] += zz * v.x;
          acc[nn][1] += zz * v.y;
          acc[nn][2] += zz * v.z;
          acc[nn][3] += zz * v.w;
        }
      }
    }
  }
  int cc = tIdC * 4;
  float4 bb = *(const float4*)(bf + cc);
  float4 o0 = *(const float4*)(ob + 0 * DD + cc);
  float4 o1 = *(const float4*)(ob + 1 * DD + cc);
  float4 o2 = *(const float4*)(ob + 2 * DD + cc);
  #pragma unroll
  for (int nn = 0; nn < 4; ++nn){
    int g2 = nbase + tIdN * 4 + nn;
    if (g2 < n){
      float a0 = att[g2 * 4 + 0], a1 = att[g2 * 4 + 1], a2 = att[g2 * 4 + 2];
      float4 rr;
      rr.x = acc[nn][0] + bb.x + a0 * o0.x + a1 * o1.x + a2 * o2.x;
      rr.y = acc[nn][1] + bb.y + a0 * o0.y + a1 * o1.y + a2 * o2.y;
      rr.z = acc[nn][2] + bb.z + a0 * o0.z + a1 * o1.z + a2 * o2.z;
      rr.w = acc[nn][3] + bb.w + a0 * o0.w + a1 * o1.w + a2 * o2.w;
      *(float4*)(out + (size_t)g2 * DD + cc) = rr;
    }
  }
}

extern "C" void kernel_launch(void* const* d_in, const int* in_sizes, int n_in,
                              void* d_out, int out_size, void* d_ws, size_t ws_size,
                              hipStream_t stream){
  const float* x   = (const float*)d_in[0];
  const int*   ei  = (const int*)d_in[1];
  const int*   dep = (const int*)d_in[2];
  const float* Wh  = (const float*)d_in[3];
  const float* bh  = (const float*)d_in[4];
  const float* Wg1 = (const float*)d_in[5];
  const float* bg1 = (const float*)d_in[6];
  const float* Wg2 = (const float*)d_in[7];
  const float* bg2 = (const float*)d_in[8];
  const float* Wa  = (const float*)d_in[9];
  const float* ba  = (const float*)d_in[10];
  const float* Wf  = (const float*)d_in[11];
  const float* bf  = (const float*)d_in[12];
  float* out = (float*)d_out;

  int N = in_sizes[0] / DD;
  int E = in_sizes[1] / 2;
  if (N <= 0) return;
  const int* row = ei;
  const int* col = ei + E;

  char* w = (char*)d_ws;
  size_t o = 0;
  auto alloc = [&](size_t bytes) -> void* {
    void* p = w + o;
    o += (bytes + 255) & ~(size_t)255;
    return p;
  };
  unsigned short* xb  = (unsigned short*)alloc((size_t)N * DD * 2);
  unsigned short* c1b = (unsigned short*)alloc((size_t)N * DD * 2);
  unsigned short* c2b = (unsigned short*)alloc((size_t)N * DD * 2);
  float* att  = (float*)alloc((size_t)N * 4 * 4);
  float* V    = (float*)alloc((size_t)3 * DD * DD * 4);
  float* ob   = (float*)alloc((size_t)3 * DD * 4);
  float* U    = (float*)alloc((size_t)3 * DD * 3 * 4);
  float* lc   = (float*)alloc(16);
  float* sw   = (float*)alloc(16);
  int*   maxd = (int*)alloc(16);
  int*   cnt  = (int*)alloc((size_t)N * 4);
  int*   offs = (int*)alloc((size_t)(N + 1) * 4);
  int*   cur  = (int*)alloc((size_t)N * 4);
  int*   srcs = (int*)alloc((size_t)E * 4);
  int*   loc  = (int*)alloc((size_t)N * 4);
  int    nb   = (N + 1023) / 1024;
  int*   btot = (int*)alloc((size_t)nb * 4);
  int*   bbase= (int*)alloc((size_t)nb * 4);

  hipMemsetAsync(maxd, 0, 4, stream);
  hipMemsetAsync(cnt, 0, (size_t)N * 4, stream);

  k_depthmax<<<128, 256, 0, stream>>>(dep, maxd, N);
  k_cast<<<(N * DD / 4 + 255) / 256, 256, 0, stream>>>(x, xb, N * DD / 4);
  k_gate<<<1, 64, 0, stream>>>(maxd, Wg1, bg1, Wg2, bg2, ba, sw, lc, (float)N / 5000.0f);
  k_combine<<<dim3(129, 3), 128, 0, stream>>>(Wh, bh, Wf, sw, V, ob);
  k_ua<<<3, 128, 0, stream>>>(Wh, bh, Wa, sw, U, lc);
  k_hist<<<(E + 255) / 256, 256, 0, stream>>>(col, cnt, E);
  k_scan1<<<nb, 1024, 0, stream>>>(cnt, loc, btot, N);
  k_scan2<<<1, 64, 0, stream>>>(btot, bbase, nb, offs, N);
  k_scan3<<<(N + 255) / 256, 256, 0, stream>>>(loc, bbase, offs, cur, N);
  k_fill<<<(E + 255) / 256, 256, 0, stream>>>(row, col, cur, srcs, E);
  int aggBlocks = (N + 7) / 8;          // one node per half-wave
  k_agg<<<aggBlocks, 256, 0, stream>>>(xb, c1b, offs, srcs, N);
  k_agg<<<aggBlocks, 256, 0, stream>>>(c1b, c2b, offs, srcs, N);
  int attBlocks = (N + 3) / 4;
  k_att<<<attBlocks, 256, 0, stream>>>(x, c1b, c2b, U, lc, att, N);
  k_out<<<(N + ONT - 1) / ONT, 256, 0, stream>>>(x, c1b, c2b, att, V, ob, bf, out, N);
}

// Round 14
// 247.029 us; speedup vs baseline: 1.5947x; 1.1349x over previous
//
#include <hip/hip_runtime.h>
#include <hip/hip_bf16.h>

#define DD 128

typedef __attribute__((ext_vector_type(8))) short bf16x8;
typedef __attribute__((ext_vector_type(4))) float f32x4;

__device__ __forceinline__ float b2f(unsigned short u){
  return __uint_as_float((unsigned int)u << 16);
}
__device__ __forceinline__ unsigned short f2b(float f){
  unsigned int u = __float_as_uint(f);
  unsigned int r = (u + 0x7FFFu + ((u >> 16) & 1u)) >> 16;   // RNE
  return (unsigned short)r;
}

// ---------------- max depth reduction ----------------
__global__ void k_depthmax(const int* __restrict__ depths, int* __restrict__ maxd, int n){
  int v = 0;
  for (int i = blockIdx.x * blockDim.x + threadIdx.x; i < n; i += gridDim.x * blockDim.x){
    int d = depths[i]; v = d > v ? d : v;
  }
  #pragma unroll
  for (int off = 32; off; off >>= 1){ int o = __shfl_xor(v, off); v = o > v ? o : v; }
  if ((threadIdx.x & 63) == 0) atomicMax(maxd, v);
}

// ---------------- cast x -> bf16 shadow ----------------
__global__ void k_cast(const float* __restrict__ x, unsigned short* __restrict__ xb, int total4){
  int i = blockIdx.x * blockDim.x + threadIdx.x;
  if (i < total4){
    float4 v = ((const float4*)x)[i];
    ushort4 w;
    w.x = f2b(v.x); w.y = f2b(v.y); w.z = f2b(v.z); w.w = f2b(v.w);
    ((ushort4*)xb)[i] = w;
  }
}

// ---------------- gate MLP: scale_weights (sw[3]), init lc = ba ----------------
__global__ void k_gate(const int* __restrict__ maxd, const float* __restrict__ Wg1,
                       const float* __restrict__ bg1, const float* __restrict__ Wg2,
                       const float* __restrict__ bg2, const float* __restrict__ ba,
                       float* __restrict__ sw, float* __restrict__ lc, float sf0){
  __shared__ float h[32];
  int t = threadIdx.x;
  float sf1 = (float)(*maxd) / 20.0f;
  if (t < 32) h[t] = fmaxf(0.0f, sf0 * Wg1[t] + sf1 * Wg1[32 + t] + bg1[t]);
  __syncthreads();
  if (t < 3){
    float s = bg2[t];
    for (int k = 0; k < 32; ++k) s += h[k] * Wg2[k * 3 + t];
    sw[t] = 1.0f / (1.0f + __expf(-s));
    lc[t] = ba[t];
  }
}

// ---------------- combined matrices: Vt (bf16, B-fragment order) and ob ----------------
// Vt layout: flat = ((kt_total*128 + col)*4 + g)*8 + j  where kt_total = i*4 + (k>>5),
// g = (k>>3)&3, j = k&7.  B-frag for lane l: col=..+ (l&15), g = l>>4 -> contiguous 16B.
__global__ void k_combine(const float* __restrict__ Wh, const float* __restrict__ bh,
                          const float* __restrict__ Wf, const float* __restrict__ sw,
                          unsigned short* __restrict__ Vt, float* __restrict__ ob){
  int k = blockIdx.x;        // 0..128 (128 == bias row)
  int i = blockIdx.y;        // hop
  int c = threadIdx.x;       // col 0..127
  float s = sw[i];
  float acc = 0.0f;
  if (k < DD){
    for (int d = 0; d < DD; ++d)
      acc += Wh[(i * DD + k) * DD + d] * Wf[(i * DD + d) * DD + c];
    int ktt = i * 4 + (k >> 5);
    int g = (k >> 3) & 3;
    int j = k & 7;
    Vt[((((size_t)ktt * DD + c) * 4 + g) << 3) + j] = f2b(s * acc);
  } else {
    for (int d = 0; d < DD; ++d)
      acc += bh[i * DD + d] * Wf[(i * DD + d) * DD + c];
    ob[i * DD + c] = s * acc;
  }
}

// ---------------- U_i = sw_i * Wh_i @ Wa_i  and lc += sw_i * bh_i @ Wa_i ----------------
__global__ void k_ua(const float* __restrict__ Wh, const float* __restrict__ bh,
                     const float* __restrict__ Wa, const float* __restrict__ sw,
                     float* __restrict__ U, float* __restrict__ lc){
  int i = blockIdx.x, k = threadIdx.x;
  float s = sw[i];
  float a0 = 0, a1 = 0, a2 = 0;
  for (int d = 0; d < DD; ++d){
    float w = Wh[(i * DD + k) * DD + d];
    a0 += w * Wa[(i * DD + d) * 3 + 0];
    a1 += w * Wa[(i * DD + d) * 3 + 1];
    a2 += w * Wa[(i * DD + d) * 3 + 2];
  }
  U[(i * DD + k) * 3 + 0] = s * a0;
  U[(i * DD + k) * 3 + 1] = s * a1;
  U[(i * DD + k) * 3 + 2] = s * a2;
  if (k < 3){
    float b = 0;
    for (int d = 0; d < DD; ++d) b += bh[i * DD + d] * Wa[(i * DD + d) * 3 + k];
    atomicAdd(&lc[k], s * b);
  }
}

// ---------------- CSR build ----------------
__global__ void k_hist(const int* __restrict__ col, int* __restrict__ cnt, int e){
  for (int i = blockIdx.x * blockDim.x + threadIdx.x; i < e; i += gridDim.x * blockDim.x)
    atomicAdd(&cnt[col[i]], 1);
}

__global__ void k_scan1(const int* __restrict__ cnt, int* __restrict__ loc,
                        int* __restrict__ btot, int n){
  __shared__ int sdata[1024];
  int t = threadIdx.x;
  int i = blockIdx.x * 1024 + t;
  int v = (i < n) ? cnt[i] : 0;
  sdata[t] = v;
  __syncthreads();
  for (int d = 1; d < 1024; d <<= 1){
    int a = (t >= d) ? sdata[t - d] : 0;
    __syncthreads();
    sdata[t] += a;
    __syncthreads();
  }
  if (i < n) loc[i] = sdata[t] - v;
  if (t == 1023) btot[blockIdx.x] = sdata[1023];
}

__global__ void k_scan2(const int* __restrict__ btot, int* __restrict__ bbase,
                        int nb, int* __restrict__ offs, int n){
  int lane = threadIdx.x & 63;
  int carry = 0;
  for (int s = 0; s < nb; s += 64){
    int idx = s + lane;
    int v = (idx < nb) ? btot[idx] : 0;
    int incl = v;
    #pragma unroll
    for (int d = 1; d < 64; d <<= 1){
      int o = __shfl_up(incl, d);
      if (lane >= d) incl += o;
    }
    if (idx < nb) bbase[idx] = carry + incl - v;
    carry += __shfl(incl, 63);
  }
  if (lane == 0) offs[n] = carry;
}

__global__ void k_scan3(const int* __restrict__ loc, const int* __restrict__ bbase,
                        int* __restrict__ offs, int* __restrict__ cur, int n){
  int i = blockIdx.x * blockDim.x + threadIdx.x;
  if (i < n){
    int ex = loc[i] + bbase[i >> 10];
    offs[i] = ex;
    cur[i] = ex;
  }
}

__global__ void k_fill(const int* __restrict__ row, const int* __restrict__ col,
                       int* __restrict__ cur, int* __restrict__ srcs, int e){
  for (int i = blockIdx.x * blockDim.x + threadIdx.x; i < e; i += gridDim.x * blockDim.x){
    int c = col[i];
    int p = atomicAdd(&cur[c], 1);
    srcs[p] = row[i];
  }
}

// ---------------- scatter_mean over bf16 rows: one node per HALF-WAVE ----------------
__global__ void k_agg(const unsigned short* __restrict__ src, unsigned short* __restrict__ dst,
                      const int* __restrict__ offs, const int* __restrict__ srcs, int n){
  int hw = (blockIdx.x * blockDim.x + threadIdx.x) >> 5;
  int lane = threadIdx.x & 31;
  int nhw = (gridDim.x * blockDim.x) >> 5;
  const ushort4* s4 = (const ushort4*)src;
  for (int node = hw; node < n; node += nhw){
    int o0 = offs[node], o1 = offs[node + 1];
    float ax = 0.0f, ay = 0.0f, az = 0.0f, aw = 0.0f;
    for (int base = o0; base < o1; base += 32){
      int m = o1 - base; if (m > 32) m = 32;
      int myidx = (base + lane < o1) ? srcs[base + lane] : 0;
      int j = 0;
      for (; j + 4 <= m; j += 4){
        int i0 = __shfl(myidx, j, 32);
        int i1 = __shfl(myidx, j + 1, 32);
        int i2 = __shfl(myidx, j + 2, 32);
        int i3 = __shfl(myidx, j + 3, 32);
        ushort4 v0 = s4[(size_t)i0 * 32 + lane];
        ushort4 v1 = s4[(size_t)i1 * 32 + lane];
        ushort4 v2 = s4[(size_t)i2 * 32 + lane];
        ushort4 v3 = s4[(size_t)i3 * 32 + lane];
        ax += (b2f(v0.x) + b2f(v1.x)) + (b2f(v2.x) + b2f(v3.x));
        ay += (b2f(v0.y) + b2f(v1.y)) + (b2f(v2.y) + b2f(v3.y));
        az += (b2f(v0.z) + b2f(v1.z)) + (b2f(v2.z) + b2f(v3.z));
        aw += (b2f(v0.w) + b2f(v1.w)) + (b2f(v2.w) + b2f(v3.w));
      }
      for (; j < m; ++j){
        int s = __shfl(myidx, j, 32);
        ushort4 v = s4[(size_t)s * 32 + lane];
        ax += b2f(v.x); ay += b2f(v.y); az += b2f(v.z); aw += b2f(v.w);
      }
    }
    float inv = 1.0f / fmaxf((float)(o1 - o0), 1.0f);
    ushort4 r;
    r.x = f2b(ax * inv); r.y = f2b(ay * inv); r.z = f2b(az * inv); r.w = f2b(aw * inv);
    ((ushort4*)dst)[(size_t)node * 32 + lane] = r;
  }
}

// ---------------- attention: logits = x@U_0 + c1@U_1 + c2@U_2 + lc ; softmax ----------------
__global__ void k_att(const float* __restrict__ c0, const unsigned short* __restrict__ c1b,
                      const unsigned short* __restrict__ c2b, const float* __restrict__ U,
                      const float* __restrict__ lc, float* __restrict__ att, int n){
  int wid = (blockIdx.x * blockDim.x + threadIdx.x) >> 6;
  int lane = threadIdx.x & 63;
  int nw = (gridDim.x * blockDim.x) >> 6;
  for (int node = wid; node < n; node += nw){
    float l0 = 0, l1 = 0, l2 = 0;
    {
      float2 v = ((const float2*)c0)[(size_t)node * 64 + lane];
      int k0 = (0 * DD + lane * 2) * 3;
      l0 += v.x * U[k0 + 0] + v.y * U[k0 + 3];
      l1 += v.x * U[k0 + 1] + v.y * U[k0 + 4];
      l2 += v.x * U[k0 + 2] + v.y * U[k0 + 5];
    }
    {
      ushort2 w = ((const ushort2*)c1b)[(size_t)node * 64 + lane];
      float vx = b2f(w.x), vy = b2f(w.y);
      int k0 = (1 * DD + lane * 2) * 3;
      l0 += vx * U[k0 + 0] + vy * U[k0 + 3];
      l1 += vx * U[k0 + 1] + vy * U[k0 + 4];
      l2 += vx * U[k0 + 2] + vy * U[k0 + 5];
    }
    {
      ushort2 w = ((const ushort2*)c2b)[(size_t)node * 64 + lane];
      float vx = b2f(w.x), vy = b2f(w.y);
      int k0 = (2 * DD + lane * 2) * 3;
      l0 += vx * U[k0 + 0] + vy * U[k0 + 3];
      l1 += vx * U[k0 + 1] + vy * U[k0 + 4];
      l2 += vx * U[k0 + 2] + vy * U[k0 + 5];
    }
    #pragma unroll
    for (int off = 32; off; off >>= 1){
      l0 += __shfl_xor(l0, off);
      l1 += __shfl_xor(l1, off);
      l2 += __shfl_xor(l2, off);
    }
    l0 += lc[0]; l1 += lc[1]; l2 += lc[2];
    float m = fmaxf(l0, fmaxf(l1, l2));
    float e0 = __expf(l0 - m), e1 = __expf(l1 - m), e2 = __expf(l2 - m);
    float inv = 1.0f / (e0 + e1 + e2);
    if (lane == 0)
      *(float4*)(att + (size_t)node * 4) = make_float4(e0 * inv, e1 * inv, e2 * inv, 0.0f);
  }
}

// ---------------- fused output GEMM via MFMA (bf16), LDS-free ----------------
// out = sum_i att_i*(c_i@V_i) + att·ob + bf.  Per wave: 16 nodes x 64 cols.
// A frag: lane holds c_i[mbase+(l&15)][kc0 + 8*(l>>4) + 0..7] (raw bf16, 16B load).
// B frag: Vt pre-arranged so lane's 16B = V[same k-slots][col].  Same assumed k-slot
// map on both sides -> result invariant to the true slot permutation.
// C/D (HW-verified): col = lane&15, row = (lane>>4)*4 + reg.
__global__ __launch_bounds__(256) void k_out(
    const unsigned short* __restrict__ xb, const unsigned short* __restrict__ c1b,
    const unsigned short* __restrict__ c2b,
    const float* __restrict__ att, const unsigned short* __restrict__ Vt,
    const float* __restrict__ ob, const float* __restrict__ bf,
    float* __restrict__ out, int n){
  int t = threadIdx.x;
  int w = t >> 6, l = t & 63;
  int ng = w & 1, ch = w >> 1;
  int mbase = blockIdx.x * 32 + ng * 16;
  int colbase = ch * 64;
  int lm = l & 15, lg = l >> 4;

  f32x4 acc[4][3];
  #pragma unroll
  for (int ct = 0; ct < 4; ++ct)
    #pragma unroll
    for (int i = 0; i < 3; ++i) acc[ct][i] = (f32x4){0.f, 0.f, 0.f, 0.f};

  int mrow = mbase + lm;
  if (mrow > n - 1) mrow = n - 1;      // clamped load row (discarded at store)

  #pragma unroll
  for (int kt = 0; kt < 12; ++kt){
    int i = kt >> 2;
    int kc0 = (kt & 3) << 5;
    const unsigned short* cb = (i == 0) ? xb : (i == 1) ? c1b : c2b;
    bf16x8 a = *(const bf16x8*)(cb + (size_t)mrow * DD + kc0 + lg * 8);
    #pragma unroll
    for (int ct = 0; ct < 4; ++ct){
      int ncol = colbase + ct * 16 + lm;
      bf16x8 b = *(const bf16x8*)(Vt + ((((size_t)kt * DD + ncol) * 4 + lg) << 3));
      acc[ct][i] = __builtin_amdgcn_mfma_f32_16x16x32_bf16(a, b, acc[ct][i], 0, 0, 0);
    }
  }

  // epilogue
  #pragma unroll
  for (int j = 0; j < 4; ++j){
    int node = mbase + lg * 4 + j;
    if (node < n){
      float4 av = *(const float4*)(att + (size_t)node * 4);
      #pragma unroll
      for (int ct = 0; ct < 4; ++ct){
        int col = colbase + ct * 16 + lm;
        float r = acc[ct][0][j] * av.x + acc[ct][1][j] * av.y + acc[ct][2][j] * av.z
                + bf[col] + av.x * ob[0 * DD + col] + av.y * ob[1 * DD + col]
                + av.z * ob[2 * DD + col];
        out[(size_t)node * DD + col] = r;
      }
    }
  }
}

extern "C" void kernel_launch(void* const* d_in, const int* in_sizes, int n_in,
                              void* d_out, int out_size, void* d_ws, size_t ws_size,
                              hipStream_t stream){
  const float* x   = (const float*)d_in[0];
  const int*   ei  = (const int*)d_in[1];
  const int*   dep = (const int*)d_in[2];
  const float* Wh  = (const float*)d_in[3];
  const float* bh  = (const float*)d_in[4];
  const float* Wg1 = (const float*)d_in[5];
  const float* bg1 = (const float*)d_in[6];
  const float* Wg2 = (const float*)d_in[7];
  const float* bg2 = (const float*)d_in[8];
  const float* Wa  = (const float*)d_in[9];
  const float* ba  = (const float*)d_in[10];
  const float* Wf  = (const float*)d_in[11];
  const float* bf  = (const float*)d_in[12];
  float* out = (float*)d_out;

  int N = in_sizes[0] / DD;
  int E = in_sizes[1] / 2;
  if (N <= 0) return;
  const int* row = ei;
  const int* col = ei + E;

  char* w = (char*)d_ws;
  size_t o = 0;
  auto alloc = [&](size_t bytes) -> void* {
    void* p = w + o;
    o += (bytes + 255) & ~(size_t)255;
    return p;
  };
  unsigned short* xb  = (unsigned short*)alloc((size_t)N * DD * 2);
  unsigned short* c1b = (unsigned short*)alloc((size_t)N * DD * 2);
  unsigned short* c2b = (unsigned short*)alloc((size_t)N * DD * 2);
  float* att  = (float*)alloc((size_t)N * 4 * 4);
  unsigned short* Vt = (unsigned short*)alloc((size_t)3 * DD * DD * 2);
  float* ob   = (float*)alloc((size_t)3 * DD * 4);
  float* U    = (float*)alloc((size_t)3 * DD * 3 * 4);
  float* lc   = (float*)alloc(16);
  float* sw   = (float*)alloc(16);
  int*   maxd = (int*)alloc(16);
  int*   cnt  = (int*)alloc((size_t)N * 4);
  int*   offs = (int*)alloc((size_t)(N + 1) * 4);
  int*   cur  = (int*)alloc((size_t)N * 4);
  int*   srcs = (int*)alloc((size_t)E * 4);
  int*   loc  = (int*)alloc((size_t)N * 4);
  int    nb   = (N + 1023) / 1024;
  int*   btot = (int*)alloc((size_t)nb * 4);
  int*   bbase= (int*)alloc((size_t)nb * 4);

  hipMemsetAsync(maxd, 0, 4, stream);
  hipMemsetAsync(cnt, 0, (size_t)N * 4, stream);

  k_depthmax<<<128, 256, 0, stream>>>(dep, maxd, N);
  k_cast<<<(N * DD / 4 + 255) / 256, 256, 0, stream>>>(x, xb, N * DD / 4);
  k_gate<<<1, 64, 0, stream>>>(maxd, Wg1, bg1, Wg2, bg2, ba, sw, lc, (float)N / 5000.0f);
  k_combine<<<dim3(129, 3), 128, 0, stream>>>(Wh, bh, Wf, sw, Vt, ob);
  k_ua<<<3, 128, 0, stream>>>(Wh, bh, Wa, sw, U, lc);
  k_hist<<<(E + 255) / 256, 256, 0, stream>>>(col, cnt, E);
  k_scan1<<<nb, 1024, 0, stream>>>(cnt, loc, btot, N);
  k_scan2<<<1, 64, 0, stream>>>(btot, bbase, nb, offs, N);
  k_scan3<<<(N + 255) / 256, 256, 0, stream>>>(loc, bbase, offs, cur, N);
  k_fill<<<(E + 255) / 256, 256, 0, stream>>>(row, col, cur, srcs, E);
  int aggBlocks = (N + 7) / 8;          // one node per half-wave
  k_agg<<<aggBlocks, 256, 0, stream>>>(xb, c1b, offs, srcs, N);
  k_agg<<<aggBlocks, 256, 0, stream>>>(c1b, c2b, offs, srcs, N);
  int attBlocks = (N + 3) / 4;
  k_att<<<attBlocks, 256, 0, stream>>>(x, c1b, c2b, U, lc, att, N);
  k_out<<<(N + 31) / 32, 256, 0, stream>>>(xb, c1b, c2b, att, Vt, ob, bf, out, N);
}